// Round 9
// baseline (109.994 us; speedup 1.0000x reference)
//
#include <hip/hip_runtime.h>

// 4-level db4 wavedec (symmetric mode) + 6 stats per band.
// One block of 512 threads per signal. Levels: 16384 -> 8195 -> 4101 -> 2054 -> 1030.
//
// V10 = V3 (90.1us, best) with ONE change, strictly OUTSIDE the hot loop:
//   band_reduce shortened to a 4-step butterfly (xor 32,16,8,4; lanes 0-3 of
//   each wave write 4 partials -> 32/band), and the finalize is wave-parallel
//   (wave w reduces band w: one LDS read + 5-step shuffle) instead of
//   thread-0-serial. Hot quad loop / load_win / tail / barriers byte-identical
//   to V3. red 0.8KB -> 3.2KB; LDS 52.4KB, still 3 blocks/CU (verified by V9's
//   counters: LDS_Block_Size 52736, occupancy 61.9%).
// HARD RULES from 6 regressions (V4 103.6 in-place barriers, V5 131.7 packed
// v2f scratch, V6 131.3 hold-in-regs spill, V7 91.8 span+swizzle neutral,
// V8 127.9 lambda spill, V9 106.9 shfl-zc exec-mask/lgkm bubble):
//   do NOT touch the hot loop: no lambdas, no outer unroll pragmas, no
//   cross-lane ops inside it, scalar accumulators, 5x float4 load_win as-is.
// Band order: [cA4, cD4, cD3, cD2, cD1] x [mean_abs, std, rms, max, energy, zc].

#define T0 16384
#define BLK 512
#define NW (BLK / 64)

// Reversed db4 decomposition filters (lax correlation == pywt convolution).
constexpr float FLO[8] = {
     0.23037781330885523f,  0.7148465705525415f,   0.6308807679295904f,
    -0.02798376941698385f, -0.18703481171888114f,  0.030841381835986965f,
     0.032883011666982945f, -0.010597401784997278f };
constexpr float FHI[8] = {
    -0.010597401784997278f, -0.032883011666982945f, 0.030841381835986965f,
     0.18703481171888114f,  -0.02798376941698385f,  -0.6308807679295904f,
     0.7148465705525415f,   -0.23037781330885523f };

// symmetric extension fold: ext index t -> valid index (single fold suffices;
// our windows stay within [-6, L+10]).
__device__ __forceinline__ float getsym(const float* __restrict__ s, int t, int L) {
    if (t < 0) t = -1 - t;
    else if (t >= L) t = 2 * L - 1 - t;
    return s[t];
}

// 1 if sign bits differ (zero-crossing). Matches sign()-diff for nonzero data.
__device__ __forceinline__ float zcstep(float p, float q) {
    return ((__float_as_int(p) ^ __float_as_int(q)) < 0) ? 1.f : 0.f;
}

// 4-step butterfly (xor 32,16,8,4): each lane ends with the sum over its
// lane%4 class; lanes 0-3 of each wave write 4 partials -> 32 per band.
// NO barrier here (deferred to finalize).
__device__ __forceinline__ void band_reduce(float sabs, float ssum, float ssq,
                                            float smax, float zc,
                                            int band, float* __restrict__ red) {
    #pragma unroll
    for (int off = 32; off >= 4; off >>= 1) {
        sabs += __shfl_xor(sabs, off, 64);
        ssum += __shfl_xor(ssum, off, 64);
        ssq  += __shfl_xor(ssq,  off, 64);
        smax  = fmaxf(smax, __shfl_xor(smax, off, 64));
        zc   += __shfl_xor(zc,   off, 64);
    }
    const int lane = (int)threadIdx.x & 63;
    if (lane < 4) {
        const int wave = (int)threadIdx.x >> 6;
        float* r = red + ((band * NW + wave) * 4 + lane) * 5;
        r[0] = sabs; r[1] = ssum; r[2] = ssq; r[3] = smax; r[4] = zc;
    }
}

// Load the 20-float window for quad k: v[j] = src_ext[8k-8+j]. Fast path is
// 5x float4 (16B aligned, 32B lane stride -> conflict-free b128 in LDS);
// boundary threads take the folded scalar path (only v[2..17] are consumed).
__device__ __forceinline__ void load_win(const float* __restrict__ src, int L, int k,
                                         float* __restrict__ v) {
    const int w = 8 * k - 8;
    if (w >= 0 && w + 20 <= L) {
        #pragma unroll
        for (int q = 0; q < 5; ++q) {
            const float4 t = *reinterpret_cast<const float4*>(src + w + 4 * q);
            v[4*q+0] = t.x; v[4*q+1] = t.y; v[4*q+2] = t.z; v[4*q+3] = t.w;
        }
    } else {
        #pragma unroll
        for (int j = 2; j < 18; ++j) v[j] = getsym(src, w + j, L);
    }
}

// a[0..3], d[0..4] (+a[4] if LAST) for one quad from window v[2..17].
// Scalar FMAs, m ascending -- proven codegen (V3).
template<bool LAST>
__device__ __forceinline__ void quad_dots(const float* __restrict__ v,
                                          float* __restrict__ a, float* __restrict__ d) {
    #pragma unroll
    for (int i = 0; i < 5; ++i) { a[i] = 0.f; d[i] = 0.f; }
    #pragma unroll
    for (int i = 0; i < 4; ++i) {
        #pragma unroll
        for (int m = 0; m < 8; ++m) {
            a[i] = fmaf(v[2*i+2+m], FLO[m], a[i]);
            d[i] = fmaf(v[2*i+2+m], FHI[m], d[i]);
        }
    }
    #pragma unroll
    for (int m = 0; m < 8; ++m) {
        d[4] = fmaf(v[10+m], FHI[m], d[4]);
        if constexpr (LAST) a[4] = fmaf(v[10+m], FLO[m], a[4]);
    }
}

// Full 5-dot version for cold tail paths.
__device__ __forceinline__ void quad_dots_tail(const float* __restrict__ v,
                                               float* __restrict__ a, float* __restrict__ d) {
    #pragma unroll
    for (int i = 0; i < 5; ++i) { a[i] = 0.f; d[i] = 0.f; }
    #pragma unroll
    for (int i = 0; i < 5; ++i) {
        #pragma unroll
        for (int m = 0; m < 8; ++m) {
            a[i] = fmaf(v[2*i+2+m], FLO[m], a[i]);
            d[i] = fmaf(v[2*i+2+m], FHI[m], d[i]);
        }
    }
}

// One DWT level, quad-per-thread, V3 shape (hot loop untouched).
// LAST: also accumulate cA stats into band 0 and skip the dst write.
template<bool LAST>
__device__ __forceinline__ void dwt_quad_level(const float* __restrict__ src, int L,
                                               float* __restrict__ dst, int o,
                                               int dband, float* __restrict__ red) {
    float sabs = 0.f, ssum = 0.f, ssq = 0.f, smax = 0.f, zc = 0.f;       // cD stats
    float sabsA = 0.f, ssumA = 0.f, ssqA = 0.f, smaxA = 0.f, zcA = 0.f;  // cA stats (LAST)
    const int nq_main = (o - 1) >> 2;   // quads with 4 valid outputs AND valid extra

    for (int k = threadIdx.x; k < nq_main; k += BLK) {
        float v[20], a[5], d[5];
        load_win(src, L, k, v);
        quad_dots<LAST>(v, a, d);
        if constexpr (!LAST) {
            *reinterpret_cast<float4*>(dst + 4 * k) = make_float4(a[0], a[1], a[2], a[3]);
        }
        #pragma unroll
        for (int i = 0; i < 4; ++i) {
            const float ad = fabsf(d[i]);
            sabs += ad; ssum += d[i]; ssq = fmaf(d[i], d[i], ssq);
            smax = fmaxf(smax, ad);
            zc += zcstep(d[i], d[i + 1]);
            if constexpr (LAST) {
                const float aa = fabsf(a[i]);
                sabsA += aa; ssumA += a[i]; ssqA = fmaf(a[i], a[i], ssqA);
                smaxA = fmaxf(smaxA, aa);
                zcA += zcstep(a[i], a[i + 1]);
            }
        }
    }

    if (threadIdx.x == BLK - 1) {       // exactly one leftover quad per level
        const int k = nq_main;
        float v[20], a[5], d[5];
        #pragma unroll
        for (int j = 2; j < 18; ++j) v[j] = getsym(src, 8 * k - 8 + j, L);
        quad_dots_tail(v, a, d);
        #pragma unroll
        for (int i = 0; i < 4; ++i) {
            const int p = 4 * k + i;
            if (p < o) {
                const float ad = fabsf(d[i]);
                sabs += ad; ssum += d[i]; ssq = fmaf(d[i], d[i], ssq);
                smax = fmaxf(smax, ad);
                if (p + 1 < o) zc += zcstep(d[i], d[i+1]);
                if constexpr (LAST) {
                    const float aa = fabsf(a[i]);
                    sabsA += aa; ssumA += a[i]; ssqA = fmaf(a[i], a[i], ssqA);
                    smaxA = fmaxf(smaxA, aa);
                    if (p + 1 < o) zcA += zcstep(a[i], a[i+1]);
                } else {
                    dst[p] = a[i];
                }
            }
        }
    }

    band_reduce(sabs, ssum, ssq, smax, zc, dband, red);
    if constexpr (LAST) band_reduce(sabsA, ssumA, ssqA, smaxA, zcA, 0, red);
}

__global__ void __launch_bounds__(BLK, 6)
wavelet_feat_kernel(const float* __restrict__ x, float* __restrict__ out) {
    __shared__ __align__(16) float A[8196];     // cA1, later cA3
    __shared__ __align__(16) float B[4104];     // cA2
    __shared__ float red[5 * 32 * 5];           // [band][partial 0..31][stat]

    const float* src0 = x + (size_t)blockIdx.x * T0;
    float* outp = out + (size_t)blockIdx.x * 30;

    // band index: 0=cA4 1=cD4 2=cD3 3=cD2 4=cD1
    dwt_quad_level<false>(src0, T0,   A, 8195, 4, red);   // L1: x -> A,  cD1
    __syncthreads();
    dwt_quad_level<false>(A,    8195, B, 4101, 3, red);   // L2: A -> B,  cD2
    __syncthreads();
    dwt_quad_level<false>(B,    4101, A, 2054, 2, red);   // L3: B -> A,  cD3
    __syncthreads();
    dwt_quad_level<true >(A,    2054, nullptr, 1030, 1, red); // L4: cD4 + cA4 stats
    __syncthreads();                                      // red[] complete

    // Finalize: wave w handles band w (parallel, replaces thread-0-serial).
    const int wave = (int)threadIdx.x >> 6, lane = (int)threadIdx.x & 63;
    if (wave < 5) {
        float a = 0.f, s = 0.f, q = 0.f, m = 0.f, z = 0.f;
        if (lane < 32) {
            const float* r = red + (wave * 32 + lane) * 5;
            a = r[0]; s = r[1]; q = r[2]; m = r[3]; z = r[4];
        }
        #pragma unroll
        for (int off = 16; off > 0; off >>= 1) {   // lanes 32-63 hold zeros
            a += __shfl_xor(a, off, 64);
            s += __shfl_xor(s, off, 64);
            q += __shfl_xor(q, off, 64);
            m  = fmaxf(m, __shfl_xor(m, off, 64));
            z += __shfl_xor(z, off, 64);
        }
        if (lane == 0) {
            const int band = wave;
            const int o = (band <= 1) ? 1030 : (band == 2 ? 2054 : (band == 3 ? 4101 : 8195));
            const float inv  = 1.0f / (float)o;
            const float mean = s * inv;
            const float var  = q * inv - mean * mean;
            float* op = outp + band * 6;
            op[0] = a * inv;                  // mean_abs
            op[1] = sqrtf(fmaxf(var, 0.f));   // std (population)
            op[2] = sqrtf(q * inv);           // rms
            op[3] = m;                        // max_abs
            op[4] = q;                        // energy
            op[5] = z * inv;                  // zero-crossing rate
        }
    }
}

extern "C" void kernel_launch(void* const* d_in, const int* in_sizes, int n_in,
                              void* d_out, int out_size, void* d_ws, size_t ws_size,
                              hipStream_t stream) {
    const float* x = (const float*)d_in[0];
    float* out = (float*)d_out;
    const int nsig = in_sizes[0] / T0;   // 64*64 = 4096
    hipLaunchKernelGGL(wavelet_feat_kernel, dim3(nsig), dim3(BLK), 0, stream, x, out);
}